// Round 5
// baseline (988.825 us; speedup 1.0000x reference)
//
#include <hip/hip_runtime.h>
#include <math.h>

#define NGRAPH 128
#define NPER   512
#define EPER   8192
#define NFEAT  4
#define NREL   5
#define DD     128
#define MAXNB  50
#define MAXW   21
#define NCLS   5

typedef unsigned short ushortT;
typedef unsigned char ucharT;

// ===================== Kernel A: build sorted in/out CSRs =====================
#define NTA 1024

__device__ __forceinline__ void scanExcl(const int* cnt, int* offs, int* tA,
                                         int* tB, int tid) {
  if (tid < NPER) tA[tid] = cnt[tid];
  __syncthreads();
  int* a = tA; int* b = tB;
  for (int d = 1; d < NPER; d <<= 1) {
    if (tid < NPER) {
      int v = a[tid];
      if (tid >= d) v += a[tid - d];
      b[tid] = v;
    }
    __syncthreads();
    int* t = a; a = b; b = t;
  }
  if (tid < NPER) offs[tid] = a[tid] - cnt[tid];
  __syncthreads();
}

__global__ __launch_bounds__(NTA, 1)
void build_csr2(const int* __restrict__ esrc, const int* __restrict__ edst,
                const int* __restrict__ etype, const float* __restrict__ x,
                ushortT* __restrict__ gBin, ushortT* __restrict__ gOut,
                int* __restrict__ pIn, int* __restrict__ pOut,
                int* __restrict__ gSE) {
  __shared__ int keyS[EPER];
  __shared__ int auxS[EPER];
  __shared__ ushortT nodS[EPER];
  __shared__ ucharT etyS[EPER];
  __shared__ int cnt[NPER], offs[NPER], fill[NPER];
  __shared__ int se[2];
  const int bid = blockIdx.x, tid = threadIdx.x;
  const int half = bid >> 7;             // 0: in-CSR, 1: out-CSR
  const int g = bid & 127;
  const int nbase = g * NPER, ebase = g * EPER;

  if (tid < NPER) { cnt[tid] = 0; fill[tid] = 0; }
  if (tid < 2) se[tid] = NPER;
  __syncthreads();

  if (half == 0) {
    for (int e = tid; e < EPER; e += NTA) {
      auxS[e] = esrc[ebase + e] - nbase;
      etyS[e] = (ucharT)etype[ebase + e];
      int d = edst[ebase + e] - nbase;
      atomicAdd(&cnt[d], 1);
    }
    __syncthreads();
    scanExcl(cnt, offs, keyS, keyS + NPER, tid);
    for (int e = tid; e < EPER; e += NTA) {
      int d = edst[ebase + e] - nbase;
      int pos = offs[d] + atomicAdd(&fill[d], 1);
      keyS[pos] = (d << 13) | e;
    }
    __syncthreads();
    for (int p = tid; p < EPER; p += NTA) {
      const int k = keyS[p];
      const int n = k >> 13;
      const int o = offs[n], c = cnt[n];
      int r = 0;
      for (int i = 0; i < c; ++i) r += (keyS[o + i] < k);
      const int e = k & (EPER - 1);
      gBin[(size_t)g * EPER + o + r] = (ushortT)((auxS[e] << 3) | (int)etyS[e]);
    }
    if (tid < NPER) pIn[nbase + tid] = (offs[tid] << 14) | cnt[tid];
  } else {
    for (int e = tid; e < EPER; e += NTA) {
      int s = esrc[ebase + e] - nbase;
      auxS[e] = s;
      atomicAdd(&cnt[s], 1);
    }
    if (tid < NPER) {
      if (x[(size_t)(nbase + tid) * NFEAT + 0] > 0.5f) atomicMin(&se[0], tid);
      if (x[(size_t)(nbase + tid) * NFEAT + 1] > 0.5f) atomicMin(&se[1], tid);
    }
    __syncthreads();
    scanExcl(cnt, offs, keyS, keyS + NPER, tid);
    for (int e = tid; e < EPER; e += NTA) {
      int s = auxS[e];
      int d = edst[ebase + e] - nbase;
      int pos = offs[s] + atomicAdd(&fill[s], 1);
      keyS[pos] = (d << 13) | e;
      nodS[pos] = (ushortT)s;
    }
    __syncthreads();
    for (int p = tid; p < EPER; p += NTA) {
      const int k = keyS[p];
      const int n = (int)nodS[p];
      const int o = offs[n], c = cnt[n];
      int r = 0;
      for (int i = 0; i < c; ++i) r += (keyS[o + i] < k);
      gOut[(size_t)g * EPER + o + r] = (ushortT)(k >> 13);
    }
    if (tid < NPER) pOut[nbase + tid] = (offs[tid] << 14) | cnt[tid];
    if (tid < 2) gSE[g * 2 + tid] = (se[tid] >= NPER) ? 0 : se[tid];
  }
}

// ===================== Kernel B: RGCN layer, fully LDS-resident gather =====================
// 2 blocks/graph x 512 thr. LDS: h-slice (whole graph, padded rows), edge window
// (contiguous in sorted CSR; staged if <= ELCAP else uniform global fallback),
// u planes, B. Arithmetic order identical to the proven absmax-0.0 kernel.
template <int FIN>
__global__ __launch_bounds__(512, 1)
void rgcn_layer4(const float* __restrict__ x, float* __restrict__ cs,
                 const ushortT* __restrict__ gBin, const int* __restrict__ pIn,
                 const float* __restrict__ bas, const float* __restrict__ cmp,
                 const float* __restrict__ rt, const float* __restrict__ bi,
                 int l) {
  constexpr int HP  = FIN + 4;          // padded h row (16B-aligned, bank-spread)
  constexpr int NK4 = (3 * FIN) / 4;    // k4 planes: u0 | u1 | h
  constexpr int LPN = FIN / 4;
  constexpr int UPL = 2 * LPN;          // u planes
  constexpr int ELCAP = 5120;
  __shared__ float hS[NPER * HP];
  __shared__ float uS[UPL * 256 * 4];
  __shared__ float BtS[NK4 * 32 * 4];
  __shared__ ushortT elS[ELCAP];
  __shared__ int pS[256];
  __shared__ float compS[NREL * 2];
  const int bid = blockIdx.x, tid = threadIdx.x;
  const int g = bid >> 1, half = bid & 1;
  const int nbase = g * NPER;
  const int nb2 = nbase + half * 256;

  // this block's contiguous edge window in the sorted in-CSR
  const int pkF = pIn[nb2], pkL = pIn[nb2 + 255];
  const int estart = pkF >> 14;
  const int eend = (pkL >> 14) + (pkL & 16383);
  const int sbase = estart & ~1;        // 4B-aligned staging base
  const int scnt = eend - sbase;
  const bool staged = (scnt <= ELCAP);

  if (staged) {
    const unsigned int* src32 =
        (const unsigned int*)(gBin + (size_t)g * EPER + sbase);
    unsigned int* dst32 = (unsigned int*)elS;
    const int nwords = (scnt + 1) >> 1;
    for (int i = tid; i < nwords; i += 512) dst32[i] = src32[i];
  }
  // stage h slice (whole graph)
  if constexpr (FIN == 4) {
    for (int n = tid; n < NPER; n += 512) {
      const float4 hv = *(const float4*)(x + (size_t)(nbase + n) * NFEAT);
      *(float4*)&hS[n * HP] = hv;
    }
  } else {
    for (int t = tid; t < NPER * 8; t += 512) {
      const int n = t >> 3, kq = t & 7;
      const float4 hv =
          *(const float4*)(cs + (size_t)(nbase + n) * DD + (l - 1) * 32 + kq * 4);
      *(float4*)&hS[n * HP + kq * 4] = hv;
    }
  }
  // stage B = [bas0; bas1; rt] as Bt[k4][o][c]
  for (int idx = tid; idx < NK4 * 128; idx += 512) {
    const int k4 = idx >> 7, rem = idx & 127;
    const int o = rem >> 2, c = rem & 3;
    const int k = k4 * 4 + c;
    float v;
    if (k < 2 * FIN) v = bas[k * 32 + o];
    else v = rt[(k - 2 * FIN) * 32 + o];
    BtS[(k4 * 32 + o) * 4 + c] = v;
  }
  if (tid < NREL * 2) compS[tid] = cmp[tid];
  if (tid < 256) {
    const int pk = pIn[nb2 + tid];
    const int off = pk >> 14, c = pk & 16383;
    pS[tid] = ((staged ? (off - sbase) : off) << 14) | c;
  }
  __syncthreads();

  const ushortT* elbase = staged ? elS : (gBin + (size_t)g * EPER);

  // ---- gather: LDS-only reads; order identical to proven kernel ----
  for (int t = tid; t < 256 * LPN; t += 512) {
    const int n = t / LPN, q = t % LPN;
    const int pk = pS[n];
    const int off = pk >> 14, c = pk & 16383;
    const float inv = 1.0f / (float)(c > 1 ? c : 1);
    const ushortT* el = elbase + off;
    const float* hq = hS + q * 4;
    float4 s0 = make_float4(0.f, 0.f, 0.f, 0.f);
    float4 s1 = make_float4(0.f, 0.f, 0.f, 0.f);
#pragma unroll 2
    for (int i = 0; i < c; ++i) {
      const int pe = (int)el[i];
      const float4 hv = *(const float4*)(hq + (pe >> 3) * HP);
      const float c0 = compS[(pe & 7) * 2], c1 = compS[(pe & 7) * 2 + 1];
      s0.x = fmaf(c0, hv.x, s0.x); s0.y = fmaf(c0, hv.y, s0.y);
      s0.z = fmaf(c0, hv.z, s0.z); s0.w = fmaf(c0, hv.w, s0.w);
      s1.x = fmaf(c1, hv.x, s1.x); s1.y = fmaf(c1, hv.y, s1.y);
      s1.z = fmaf(c1, hv.z, s1.z); s1.w = fmaf(c1, hv.w, s1.w);
    }
    s0.x *= inv; s0.y *= inv; s0.z *= inv; s0.w *= inv;
    s1.x *= inv; s1.y *= inv; s1.z *= inv; s1.w *= inv;
    *(float4*)&uS[(q * 256 + n) * 4] = s0;
    *(float4*)&uS[((LPN + q) * 256 + n) * 4] = s1;
  }
  __syncthreads();

  // ---- GEMM: thread tile 2 nodes x 8 outs (proven mapping, 0 conflicts) ----
  const int ot = (tid >> 4) & 3;
  const int nt = (tid & 15) | ((tid >> 6) << 4);
  const int n0 = 2 * nt, o0 = 8 * ot;
  float acc[2][8];
#pragma unroll
  for (int i = 0; i < 2; ++i)
#pragma unroll
    for (int j = 0; j < 8; ++j) acc[i][j] = 0.f;
  const int hb0 = (half * 256 + n0) * HP;
#pragma unroll
  for (int k4 = 0; k4 < NK4; ++k4) {
    float4 a0, a1;
    if (k4 < UPL) {
      a0 = *(const float4*)&uS[(k4 * 256 + n0) * 4];
      a1 = *(const float4*)&uS[(k4 * 256 + n0 + 1) * 4];
    } else {
      const int kq = (k4 - UPL) * 4;
      a0 = *(const float4*)&hS[hb0 + kq];
      a1 = *(const float4*)&hS[hb0 + HP + kq];
    }
#pragma unroll
    for (int j = 0; j < 8; ++j) {
      const float4 b = *(const float4*)&BtS[(k4 * 32 + o0 + j) * 4];
      acc[0][j] = fmaf(a0.x, b.x, acc[0][j]);
      acc[0][j] = fmaf(a0.y, b.y, acc[0][j]);
      acc[0][j] = fmaf(a0.z, b.z, acc[0][j]);
      acc[0][j] = fmaf(a0.w, b.w, acc[0][j]);
      acc[1][j] = fmaf(a1.x, b.x, acc[1][j]);
      acc[1][j] = fmaf(a1.y, b.y, acc[1][j]);
      acc[1][j] = fmaf(a1.z, b.z, acc[1][j]);
      acc[1][j] = fmaf(a1.w, b.w, acc[1][j]);
    }
  }
#pragma unroll
  for (int i = 0; i < 2; ++i) {
    float4 w0, w1;
    w0.x = tanhf(acc[i][0] + bi[o0 + 0]); w0.y = tanhf(acc[i][1] + bi[o0 + 1]);
    w0.z = tanhf(acc[i][2] + bi[o0 + 2]); w0.w = tanhf(acc[i][3] + bi[o0 + 3]);
    w1.x = tanhf(acc[i][4] + bi[o0 + 4]); w1.y = tanhf(acc[i][5] + bi[o0 + 5]);
    w1.z = tanhf(acc[i][6] + bi[o0 + 6]); w1.w = tanhf(acc[i][7] + bi[o0 + 7]);
    float* dst = cs + (size_t)(nb2 + n0 + i) * DD + l * 32 + o0;
    *(float4*)dst = w0;
    *(float4*)(dst + 4) = w1;
  }
}

// ===================== Kernel C: walk + MLP head (proven round-4) =====================
__global__ __launch_bounds__(256, 1)
void walk_head2(const float* __restrict__ cs, const ushortT* __restrict__ gOut,
                const int* __restrict__ pOut, const int* __restrict__ gSE,
                const float* __restrict__ walk_w, const float* __restrict__ walk_b,
                const float* __restrict__ lin1_w, const float* __restrict__ lin1_b,
                const float* __restrict__ lin2_w, const float* __restrict__ lin2_b,
                float* __restrict__ out) {
  __shared__ float wT[DD * 65];
  __shared__ float wb[64];
  __shared__ ushortT gOutS[EPER];
  __shared__ int pOutS[NPER];
  __shared__ int trav[NPER];
  __shared__ float scratch[MAXNB * DD];
  __shared__ float accS[DD];
  __shared__ float part[4 * 64];
  __shared__ float hidS[DD], pooledS[DD], logitsS[8];
  __shared__ int scal[8];
  const int g = blockIdx.x, tid = threadIdx.x;
  const int nbase = g * NPER;
  const float4* cs4 = (const float4*)cs;

  for (int i = tid; i < DD * 64; i += 256) {
    const int j = i >> 7, k = i & 127;
    wT[k * 65 + j] = walk_w[j * DD + k];
  }
  if (tid < 64) {
    wb[tid] = (tid < MAXNB) ? walk_b[tid] : 0.f;
    for (int k = 0; k < DD; ++k)
      if (tid >= MAXNB) wT[k * 65 + tid] = 0.f;
  }
  {
    const unsigned int* g32 = (const unsigned int*)(gOut + (size_t)g * EPER);
    unsigned int* s32 = (unsigned int*)gOutS;
    for (int i = tid; i < EPER / 2; i += 256) s32[i] = g32[i];
    for (int i = tid; i < NPER; i += 256) {
      pOutS[i] = pOut[nbase + i];
      trav[i] = 0;
    }
  }
  __syncthreads();
  const int startN = gSE[2 * g];
  const int endN = gSE[2 * g + 1];
  if (tid == 0) { scal[0] = startN; scal[1] = 0; scal[6] = 0; trav[startN] = 1; }
  if (tid < DD) accS[tid] = cs[(size_t)(nbase + startN) * DD + tid];
  __syncthreads();

  for (int step = 0; step < MAXW; ++step) {
    const int doneF = scal[1];
    int jmax = 0;
    if (!doneF) {
      const int node = scal[0];
      const int pk = pOutS[node];
      const int off = pk >> 14, c = pk & 16383;
      jmax = (c < MAXNB) ? c : MAXNB;
      const int nq = jmax * 32;
      float4 pf0, pf1, pf2, pf3, pf4, pf5, pf6;
      const int q0 = tid, q1 = tid + 256, q2 = tid + 512, q3 = tid + 768;
      const int q4 = tid + 1024, q5 = tid + 1280, q6 = tid + 1536;
      if (q0 < nq) pf0 = cs4[(size_t)(nbase + (int)gOutS[off + (q0 >> 5)]) * 32 + (q0 & 31)];
      if (q1 < nq) pf1 = cs4[(size_t)(nbase + (int)gOutS[off + (q1 >> 5)]) * 32 + (q1 & 31)];
      if (q2 < nq) pf2 = cs4[(size_t)(nbase + (int)gOutS[off + (q2 >> 5)]) * 32 + (q2 & 31)];
      if (q3 < nq) pf3 = cs4[(size_t)(nbase + (int)gOutS[off + (q3 >> 5)]) * 32 + (q3 & 31)];
      if (q4 < nq) pf4 = cs4[(size_t)(nbase + (int)gOutS[off + (q4 >> 5)]) * 32 + (q4 & 31)];
      if (q5 < nq) pf5 = cs4[(size_t)(nbase + (int)gOutS[off + (q5 >> 5)]) * 32 + (q5 & 31)];
      if (q6 < nq) pf6 = cs4[(size_t)(nbase + (int)gOutS[off + (q6 >> 5)]) * 32 + (q6 & 31)];
      {
        const int w = tid >> 6, j = tid & 63, k0 = w * 32;
        float s = 0.f;
#pragma unroll
        for (int k = 0; k < 32; ++k) s += wT[(k0 + k) * 65 + j] * accS[k0 + k];
        part[w * 64 + j] = s;
      }
      float4* scr4 = (float4*)scratch;
      if (q0 < nq) scr4[q0] = pf0;
      if (q1 < nq) scr4[q1] = pf1;
      if (q2 < nq) scr4[q2] = pf2;
      if (q3 < nq) scr4[q3] = pf3;
      if (q4 < nq) scr4[q4] = pf4;
      if (q5 < nq) scr4[q5] = pf5;
      if (q6 < nq) scr4[q6] = pf6;
    }
    __syncthreads();
    if (doneF) {
      if (tid == 0) scal[2] = 0;
    } else if (tid < 64) {
      const int j = tid;
      float lg = part[j] + part[64 + j] + part[128 + j] + part[192 + j];
      lg += wb[j];
      const int node = scal[0];
      const int pk = pOutS[node];
      const int off = pk >> 14, c = pk & 16383;
      const int jm = (c < MAXNB) ? c : MAXNB;
      float myval = -INFINITY;
      if (j < jm) {
        const int nb = (int)gOutS[off + j];
        if (!trav[nb]) myval = lg;
      }
      int myidx = j;
#pragma unroll
      for (int o = 1; o < 64; o <<= 1) {
        const float ov = __shfl_xor(myval, o, 64);
        const int oi = __shfl_xor(myidx, o, 64);
        if (ov > myval || (ov == myval && oi < myidx)) { myval = ov; myidx = oi; }
      }
      if (j == 0) {
        const int no_nbr = (c == 0);
        const int sel = no_nbr ? (NPER - 1) : (int)gOutS[off + myidx];
        scal[2] = 1;
        scal[3] = no_nbr ? endN : sel;
        scal[4] = no_nbr ? -1 : myidx;
        if (!no_nbr) { trav[sel] = 1; scal[0] = sel; }
        if (no_nbr || sel == endN) scal[1] = 1;
      }
    }
    __syncthreads();
    if (scal[2] && tid < DD) {
      const int si = scal[4];
      if (si >= 0) accS[tid] += scratch[si * DD + tid];
      else accS[tid] += cs[(size_t)(nbase + scal[3]) * DD + tid];
    }
    __syncthreads();
  }

  for (int i = tid; i < NPER; i += 256)
    if (trav[i]) atomicAdd(&scal[6], 1);
  __syncthreads();
  {
    const float tc = (float)scal[6];
    if (tid < DD) pooledS[tid] = accS[tid] / tc;
  }
  __syncthreads();
  if (tid < DD) {
    const float4* w4 = (const float4*)(lin1_w + (size_t)tid * DD);
    float s = lin1_b[tid];
#pragma unroll 8
    for (int k4 = 0; k4 < DD / 4; ++k4) {
      const float4 wv = w4[k4];
      s += wv.x * pooledS[k4 * 4 + 0] + wv.y * pooledS[k4 * 4 + 1]
         + wv.z * pooledS[k4 * 4 + 2] + wv.w * pooledS[k4 * 4 + 3];
    }
    hidS[tid] = fmaxf(s, 0.f);
  }
  __syncthreads();
  if (tid < NCLS) {
    const float4* w4 = (const float4*)(lin2_w + (size_t)tid * DD);
    float s = lin2_b[tid];
#pragma unroll 8
    for (int k4 = 0; k4 < DD / 4; ++k4) {
      const float4 wv = w4[k4];
      s += wv.x * hidS[k4 * 4 + 0] + wv.y * hidS[k4 * 4 + 1]
         + wv.z * hidS[k4 * 4 + 2] + wv.w * hidS[k4 * 4 + 3];
    }
    logitsS[tid] = s;
  }
  __syncthreads();
  if (tid < NCLS) {
    float m = logitsS[0];
    for (int c = 1; c < NCLS; ++c) m = fmaxf(m, logitsS[c]);
    float sum = 0.f;
    for (int c = 0; c < NCLS; ++c) sum += expf(logitsS[c] - m);
    const float lse = m + logf(sum);
    out[g * NCLS + tid] = logitsS[tid] - lse;
  }
}

extern "C" void kernel_launch(void* const* d_in, const int* in_sizes, int n_in,
                              void* d_out, int out_size, void* d_ws, size_t ws_size,
                              hipStream_t stream) {
  const float* x = (const float*)d_in[0];
  const int* ei = (const int*)d_in[1];
  const int E = in_sizes[1] / 2;
  const int* esrc = ei;
  const int* edst = ei + E;
  const int* et = (const int*)d_in[2];

  char* ws = (char*)d_ws;
  float* cs = (float*)ws;
  size_t off = (size_t)NGRAPH * NPER * DD * sizeof(float);
  ushortT* gBin = (ushortT*)(ws + off); off += (size_t)NGRAPH * EPER * sizeof(ushortT);
  ushortT* gOut = (ushortT*)(ws + off); off += (size_t)NGRAPH * EPER * sizeof(ushortT);
  int* pIn = (int*)(ws + off); off += (size_t)NGRAPH * NPER * sizeof(int);
  int* pOut = (int*)(ws + off); off += (size_t)NGRAPH * NPER * sizeof(int);
  int* gSE = (int*)(ws + off); off += (size_t)NGRAPH * 2 * sizeof(int);

  build_csr2<<<dim3(2 * NGRAPH), dim3(NTA), 0, stream>>>(esrc, edst, et, x, gBin,
                                                         gOut, pIn, pOut, gSE);
  rgcn_layer4<NFEAT><<<dim3(2 * NGRAPH), dim3(512), 0, stream>>>(
      x, cs, gBin, pIn, (const float*)d_in[4], (const float*)d_in[5],
      (const float*)d_in[6], (const float*)d_in[7], 0);
  rgcn_layer4<32><<<dim3(2 * NGRAPH), dim3(512), 0, stream>>>(
      x, cs, gBin, pIn, (const float*)d_in[8], (const float*)d_in[9],
      (const float*)d_in[10], (const float*)d_in[11], 1);
  rgcn_layer4<32><<<dim3(2 * NGRAPH), dim3(512), 0, stream>>>(
      x, cs, gBin, pIn, (const float*)d_in[12], (const float*)d_in[13],
      (const float*)d_in[14], (const float*)d_in[15], 2);
  rgcn_layer4<32><<<dim3(2 * NGRAPH), dim3(512), 0, stream>>>(
      x, cs, gBin, pIn, (const float*)d_in[16], (const float*)d_in[17],
      (const float*)d_in[18], (const float*)d_in[19], 3);
  walk_head2<<<dim3(NGRAPH), dim3(256), 0, stream>>>(
      cs, gOut, pOut, gSE, (const float*)d_in[20], (const float*)d_in[21],
      (const float*)d_in[22], (const float*)d_in[23], (const float*)d_in[24],
      (const float*)d_in[25], (float*)d_out);
}

// Round 6
// 750.808 us; speedup vs baseline: 1.3170x; 1.3170x over previous
//
#include <hip/hip_runtime.h>
#include <math.h>

#define NGRAPH 128
#define NPER   512
#define EPER   8192
#define NFEAT  4
#define NREL   5
#define DD     128
#define MAXNB  50
#define MAXW   21
#define NCLS   5

typedef unsigned short ushortT;
typedef unsigned char ucharT;

// ===================== Kernel A: build sorted in/out CSRs (proven) =====================
#define NTA 1024

__device__ __forceinline__ void scanExcl(const int* cnt, int* offs, int* tA,
                                         int* tB, int tid) {
  if (tid < NPER) tA[tid] = cnt[tid];
  __syncthreads();
  int* a = tA; int* b = tB;
  for (int d = 1; d < NPER; d <<= 1) {
    if (tid < NPER) {
      int v = a[tid];
      if (tid >= d) v += a[tid - d];
      b[tid] = v;
    }
    __syncthreads();
    int* t = a; a = b; b = t;
  }
  if (tid < NPER) offs[tid] = a[tid] - cnt[tid];
  __syncthreads();
}

__global__ __launch_bounds__(NTA, 1)
void build_csr2(const int* __restrict__ esrc, const int* __restrict__ edst,
                const int* __restrict__ etype, const float* __restrict__ x,
                ushortT* __restrict__ gBin, ushortT* __restrict__ gOut,
                int* __restrict__ pIn, int* __restrict__ pOut,
                int* __restrict__ gSE) {
  __shared__ int keyS[EPER];
  __shared__ int auxS[EPER];
  __shared__ ushortT nodS[EPER];
  __shared__ ucharT etyS[EPER];
  __shared__ int cnt[NPER], offs[NPER], fill[NPER];
  __shared__ int se[2];
  const int bid = blockIdx.x, tid = threadIdx.x;
  const int half = bid >> 7;             // 0: in-CSR, 1: out-CSR
  const int g = bid & 127;
  const int nbase = g * NPER, ebase = g * EPER;

  if (tid < NPER) { cnt[tid] = 0; fill[tid] = 0; }
  if (tid < 2) se[tid] = NPER;
  __syncthreads();

  if (half == 0) {
    for (int e = tid; e < EPER; e += NTA) {
      auxS[e] = esrc[ebase + e] - nbase;
      etyS[e] = (ucharT)etype[ebase + e];
      int d = edst[ebase + e] - nbase;
      atomicAdd(&cnt[d], 1);
    }
    __syncthreads();
    scanExcl(cnt, offs, keyS, keyS + NPER, tid);
    for (int e = tid; e < EPER; e += NTA) {
      int d = edst[ebase + e] - nbase;
      int pos = offs[d] + atomicAdd(&fill[d], 1);
      keyS[pos] = (d << 13) | e;
    }
    __syncthreads();
    for (int p = tid; p < EPER; p += NTA) {
      const int k = keyS[p];
      const int n = k >> 13;
      const int o = offs[n], c = cnt[n];
      int r = 0;
      for (int i = 0; i < c; ++i) r += (keyS[o + i] < k);
      const int e = k & (EPER - 1);
      gBin[(size_t)g * EPER + o + r] = (ushortT)((auxS[e] << 3) | (int)etyS[e]);
    }
    if (tid < NPER) pIn[nbase + tid] = (offs[tid] << 14) | cnt[tid];
  } else {
    for (int e = tid; e < EPER; e += NTA) {
      int s = esrc[ebase + e] - nbase;
      auxS[e] = s;
      atomicAdd(&cnt[s], 1);
    }
    if (tid < NPER) {
      if (x[(size_t)(nbase + tid) * NFEAT + 0] > 0.5f) atomicMin(&se[0], tid);
      if (x[(size_t)(nbase + tid) * NFEAT + 1] > 0.5f) atomicMin(&se[1], tid);
    }
    __syncthreads();
    scanExcl(cnt, offs, keyS, keyS + NPER, tid);
    for (int e = tid; e < EPER; e += NTA) {
      int s = auxS[e];
      int d = edst[ebase + e] - nbase;
      int pos = offs[s] + atomicAdd(&fill[s], 1);
      keyS[pos] = (d << 13) | e;
      nodS[pos] = (ushortT)s;
    }
    __syncthreads();
    for (int p = tid; p < EPER; p += NTA) {
      const int k = keyS[p];
      const int n = (int)nodS[p];
      const int o = offs[n], c = cnt[n];
      int r = 0;
      for (int i = 0; i < c; ++i) r += (keyS[o + i] < k);
      gOut[(size_t)g * EPER + o + r] = (ushortT)(k >> 13);
    }
    if (tid < NPER) pOut[nbase + tid] = (offs[tid] << 14) | cnt[tid];
    if (tid < 2) gSE[g * 2 + tid] = (se[tid] >= NPER) ? 0 : se[tid];
  }
}

// ===================== Kernel B: RGCN layer, LDS-h gather, <=119 KB LDS =====================
// 2 blocks/graph x 512 thr. hS = whole-graph h slice (padded rows, HP=FIN+4).
// Two 128-node chunks: gather (LDS-h reads, global ushort edge stream) -> uS,
// then GEMM (tile 2 nodes x 4 outs). Accumulation orders bit-identical to the
// proven absmax-0.0 kernels: edges i ascending; k = [u0 0..FIN)[u1][h], x,y,z,w.
template <int FIN>
__global__ __launch_bounds__(512, 1)
void rgcn_layer5(const float* __restrict__ x, float* __restrict__ cs,
                 const ushortT* __restrict__ gBin, const int* __restrict__ pIn,
                 const float* __restrict__ bas, const float* __restrict__ cmp,
                 const float* __restrict__ rt, const float* __restrict__ bi,
                 int l) {
  constexpr int HP  = FIN + 4;          // padded row: bank-rotates by 4/node
  constexpr int LPN = FIN / 4;          // quads per node
  constexpr int UPL = 2 * LPN;          // u planes (u0,u1)
  constexpr int NK4 = 3 * LPN;          // + h planes
  __shared__ float hS[NPER * HP];       // 73,728 B (FIN=32)
  __shared__ float uS[UPL * 128 * 4];   // 32,768 B
  __shared__ float BtS[NK4 * 32 * 4];   // 12,288 B
  __shared__ float compS[NREL * 2];
  const int bid = blockIdx.x, tid = threadIdx.x;
  const int g = bid >> 1, half = bid & 1;
  const int nbase = g * NPER;

  // ---- stage B = [bas0; bas1; rt] as Bt[k4][o][c] ----
  for (int idx = tid; idx < NK4 * 128; idx += 512) {
    const int k4 = idx >> 7, rem = idx & 127;
    const int o = rem >> 2, c = rem & 3;
    const int k = k4 * 4 + c;
    const float v = (k < 2 * FIN) ? bas[k * 32 + o] : rt[(k - 2 * FIN) * 32 + o];
    BtS[(k4 * 32 + o) * 4 + c] = v;
  }
  if (tid < NREL * 2) compS[tid] = cmp[tid];
  // ---- stage whole-graph h slice ----
  if constexpr (FIN == 4) {
    for (int n = tid; n < NPER; n += 512)
      *(float4*)&hS[n * HP] = *(const float4*)(x + (size_t)(nbase + n) * NFEAT);
  } else {
    for (int t = tid; t < NPER * 8; t += 512) {
      const int n = t >> 3, kq = t & 7;
      *(float4*)&hS[n * HP + kq * 4] =
          *(const float4*)(cs + (size_t)(nbase + n) * DD + (l - 1) * 32 + kq * 4);
    }
  }
  __syncthreads();

  for (int c2 = 0; c2 < 2; ++c2) {
    const int cb = half * 256 + c2 * 128;    // chunk's first graph-local node

    // ---- gather: u_b[n][quad q] over sorted in-edges; h from LDS ----
    for (int t = tid; t < 128 * LPN; t += 512) {
      const int n = t / LPN, q = t % LPN;
      const int pk = pIn[nbase + cb + n];
      const int off = pk >> 14, c = pk & 16383;
      const float inv = 1.0f / (float)(c > 1 ? c : 1);
      const ushortT* el = gBin + (size_t)g * EPER + off;
      const float* hq = hS + q * 4;
      float4 s0 = make_float4(0.f, 0.f, 0.f, 0.f);
      float4 s1 = make_float4(0.f, 0.f, 0.f, 0.f);
      for (int i = 0; i < c; ++i) {
        const int pe = (int)el[i];
        const float4 hv = *(const float4*)(hq + (pe >> 3) * HP);
        const float c0 = compS[(pe & 7) * 2], c1 = compS[(pe & 7) * 2 + 1];
        s0.x = fmaf(c0, hv.x, s0.x); s0.y = fmaf(c0, hv.y, s0.y);
        s0.z = fmaf(c0, hv.z, s0.z); s0.w = fmaf(c0, hv.w, s0.w);
        s1.x = fmaf(c1, hv.x, s1.x); s1.y = fmaf(c1, hv.y, s1.y);
        s1.z = fmaf(c1, hv.z, s1.z); s1.w = fmaf(c1, hv.w, s1.w);
      }
      s0.x *= inv; s0.y *= inv; s0.z *= inv; s0.w *= inv;
      s1.x *= inv; s1.y *= inv; s1.z *= inv; s1.w *= inv;
      *(float4*)&uS[(q * 128 + n) * 4] = s0;
      *(float4*)&uS[((LPN + q) * 128 + n) * 4] = s1;
    }
    __syncthreads();

    // ---- GEMM: tile 2 nodes x 4 outs; 64 pairs x 8 o-groups = 512 thr ----
    {
      const int og = tid & 7, pr = tid >> 3;
      const int n0 = pr * 2, o0 = og * 4;
      float acc[2][4];
#pragma unroll
      for (int i = 0; i < 2; ++i)
#pragma unroll
        for (int j = 0; j < 4; ++j) acc[i][j] = 0.f;
      const int hb0 = (cb + n0) * HP;
#pragma unroll
      for (int k4 = 0; k4 < NK4; ++k4) {
        float4 a0, a1;
        if (k4 < UPL) {
          a0 = *(const float4*)&uS[(k4 * 128 + n0) * 4];
          a1 = *(const float4*)&uS[(k4 * 128 + n0 + 1) * 4];
        } else {
          const int kq = (k4 - UPL) * 4;
          a0 = *(const float4*)&hS[hb0 + kq];
          a1 = *(const float4*)&hS[hb0 + HP + kq];
        }
#pragma unroll
        for (int j = 0; j < 4; ++j) {
          const float4 b = *(const float4*)&BtS[(k4 * 32 + o0 + j) * 4];
          acc[0][j] = fmaf(a0.x, b.x, acc[0][j]);
          acc[0][j] = fmaf(a0.y, b.y, acc[0][j]);
          acc[0][j] = fmaf(a0.z, b.z, acc[0][j]);
          acc[0][j] = fmaf(a0.w, b.w, acc[0][j]);
          acc[1][j] = fmaf(a1.x, b.x, acc[1][j]);
          acc[1][j] = fmaf(a1.y, b.y, acc[1][j]);
          acc[1][j] = fmaf(a1.z, b.z, acc[1][j]);
          acc[1][j] = fmaf(a1.w, b.w, acc[1][j]);
        }
      }
#pragma unroll
      for (int i = 0; i < 2; ++i) {
        float4 w0;
        w0.x = tanhf(acc[i][0] + bi[o0 + 0]);
        w0.y = tanhf(acc[i][1] + bi[o0 + 1]);
        w0.z = tanhf(acc[i][2] + bi[o0 + 2]);
        w0.w = tanhf(acc[i][3] + bi[o0 + 3]);
        *(float4*)(cs + (size_t)(nbase + cb + n0 + i) * DD + l * 32 + o0) = w0;
      }
    }
    __syncthreads();
  }
}

// ===================== Kernel C: walk + MLP head (proven) =====================
__global__ __launch_bounds__(256, 1)
void walk_head2(const float* __restrict__ cs, const ushortT* __restrict__ gOut,
                const int* __restrict__ pOut, const int* __restrict__ gSE,
                const float* __restrict__ walk_w, const float* __restrict__ walk_b,
                const float* __restrict__ lin1_w, const float* __restrict__ lin1_b,
                const float* __restrict__ lin2_w, const float* __restrict__ lin2_b,
                float* __restrict__ out) {
  __shared__ float wT[DD * 65];
  __shared__ float wb[64];
  __shared__ ushortT gOutS[EPER];
  __shared__ int pOutS[NPER];
  __shared__ int trav[NPER];
  __shared__ float scratch[MAXNB * DD];
  __shared__ float accS[DD];
  __shared__ float part[4 * 64];
  __shared__ float hidS[DD], pooledS[DD], logitsS[8];
  __shared__ int scal[8];
  const int g = blockIdx.x, tid = threadIdx.x;
  const int nbase = g * NPER;
  const float4* cs4 = (const float4*)cs;

  for (int i = tid; i < DD * 64; i += 256) {
    const int j = i >> 7, k = i & 127;
    wT[k * 65 + j] = walk_w[j * DD + k];
  }
  if (tid < 64) {
    wb[tid] = (tid < MAXNB) ? walk_b[tid] : 0.f;
    for (int k = 0; k < DD; ++k)
      if (tid >= MAXNB) wT[k * 65 + tid] = 0.f;
  }
  {
    const unsigned int* g32 = (const unsigned int*)(gOut + (size_t)g * EPER);
    unsigned int* s32 = (unsigned int*)gOutS;
    for (int i = tid; i < EPER / 2; i += 256) s32[i] = g32[i];
    for (int i = tid; i < NPER; i += 256) {
      pOutS[i] = pOut[nbase + i];
      trav[i] = 0;
    }
  }
  __syncthreads();
  const int startN = gSE[2 * g];
  const int endN = gSE[2 * g + 1];
  if (tid == 0) { scal[0] = startN; scal[1] = 0; scal[6] = 0; trav[startN] = 1; }
  if (tid < DD) accS[tid] = cs[(size_t)(nbase + startN) * DD + tid];
  __syncthreads();

  for (int step = 0; step < MAXW; ++step) {
    const int doneF = scal[1];
    int jmax = 0;
    if (!doneF) {
      const int node = scal[0];
      const int pk = pOutS[node];
      const int off = pk >> 14, c = pk & 16383;
      jmax = (c < MAXNB) ? c : MAXNB;
      const int nq = jmax * 32;
      float4 pf0, pf1, pf2, pf3, pf4, pf5, pf6;
      const int q0 = tid, q1 = tid + 256, q2 = tid + 512, q3 = tid + 768;
      const int q4 = tid + 1024, q5 = tid + 1280, q6 = tid + 1536;
      if (q0 < nq) pf0 = cs4[(size_t)(nbase + (int)gOutS[off + (q0 >> 5)]) * 32 + (q0 & 31)];
      if (q1 < nq) pf1 = cs4[(size_t)(nbase + (int)gOutS[off + (q1 >> 5)]) * 32 + (q1 & 31)];
      if (q2 < nq) pf2 = cs4[(size_t)(nbase + (int)gOutS[off + (q2 >> 5)]) * 32 + (q2 & 31)];
      if (q3 < nq) pf3 = cs4[(size_t)(nbase + (int)gOutS[off + (q3 >> 5)]) * 32 + (q3 & 31)];
      if (q4 < nq) pf4 = cs4[(size_t)(nbase + (int)gOutS[off + (q4 >> 5)]) * 32 + (q4 & 31)];
      if (q5 < nq) pf5 = cs4[(size_t)(nbase + (int)gOutS[off + (q5 >> 5)]) * 32 + (q5 & 31)];
      if (q6 < nq) pf6 = cs4[(size_t)(nbase + (int)gOutS[off + (q6 >> 5)]) * 32 + (q6 & 31)];
      {
        const int w = tid >> 6, j = tid & 63, k0 = w * 32;
        float s = 0.f;
#pragma unroll
        for (int k = 0; k < 32; ++k) s += wT[(k0 + k) * 65 + j] * accS[k0 + k];
        part[w * 64 + j] = s;
      }
      float4* scr4 = (float4*)scratch;
      if (q0 < nq) scr4[q0] = pf0;
      if (q1 < nq) scr4[q1] = pf1;
      if (q2 < nq) scr4[q2] = pf2;
      if (q3 < nq) scr4[q3] = pf3;
      if (q4 < nq) scr4[q4] = pf4;
      if (q5 < nq) scr4[q5] = pf5;
      if (q6 < nq) scr4[q6] = pf6;
    }
    __syncthreads();
    if (doneF) {
      if (tid == 0) scal[2] = 0;
    } else if (tid < 64) {
      const int j = tid;
      float lg = part[j] + part[64 + j] + part[128 + j] + part[192 + j];
      lg += wb[j];
      const int node = scal[0];
      const int pk = pOutS[node];
      const int off = pk >> 14, c = pk & 16383;
      const int jm = (c < MAXNB) ? c : MAXNB;
      float myval = -INFINITY;
      if (j < jm) {
        const int nb = (int)gOutS[off + j];
        if (!trav[nb]) myval = lg;
      }
      int myidx = j;
#pragma unroll
      for (int o = 1; o < 64; o <<= 1) {
        const float ov = __shfl_xor(myval, o, 64);
        const int oi = __shfl_xor(myidx, o, 64);
        if (ov > myval || (ov == myval && oi < myidx)) { myval = ov; myidx = oi; }
      }
      if (j == 0) {
        const int no_nbr = (c == 0);
        const int sel = no_nbr ? (NPER - 1) : (int)gOutS[off + myidx];
        scal[2] = 1;
        scal[3] = no_nbr ? endN : sel;
        scal[4] = no_nbr ? -1 : myidx;
        if (!no_nbr) { trav[sel] = 1; scal[0] = sel; }
        if (no_nbr || sel == endN) scal[1] = 1;
      }
    }
    __syncthreads();
    if (scal[2] && tid < DD) {
      const int si = scal[4];
      if (si >= 0) accS[tid] += scratch[si * DD + tid];
      else accS[tid] += cs[(size_t)(nbase + scal[3]) * DD + tid];
    }
    __syncthreads();
  }

  for (int i = tid; i < NPER; i += 256)
    if (trav[i]) atomicAdd(&scal[6], 1);
  __syncthreads();
  {
    const float tc = (float)scal[6];
    if (tid < DD) pooledS[tid] = accS[tid] / tc;
  }
  __syncthreads();
  if (tid < DD) {
    const float4* w4 = (const float4*)(lin1_w + (size_t)tid * DD);
    float s = lin1_b[tid];
#pragma unroll 8
    for (int k4 = 0; k4 < DD / 4; ++k4) {
      const float4 wv = w4[k4];
      s += wv.x * pooledS[k4 * 4 + 0] + wv.y * pooledS[k4 * 4 + 1]
         + wv.z * pooledS[k4 * 4 + 2] + wv.w * pooledS[k4 * 4 + 3];
    }
    hidS[tid] = fmaxf(s, 0.f);
  }
  __syncthreads();
  if (tid < NCLS) {
    const float4* w4 = (const float4*)(lin2_w + (size_t)tid * DD);
    float s = lin2_b[tid];
#pragma unroll 8
    for (int k4 = 0; k4 < DD / 4; ++k4) {
      const float4 wv = w4[k4];
      s += wv.x * hidS[k4 * 4 + 0] + wv.y * hidS[k4 * 4 + 1]
         + wv.z * hidS[k4 * 4 + 2] + wv.w * hidS[k4 * 4 + 3];
    }
    logitsS[tid] = s;
  }
  __syncthreads();
  if (tid < NCLS) {
    float m = logitsS[0];
    for (int c = 1; c < NCLS; ++c) m = fmaxf(m, logitsS[c]);
    float sum = 0.f;
    for (int c = 0; c < NCLS; ++c) sum += expf(logitsS[c] - m);
    const float lse = m + logf(sum);
    out[g * NCLS + tid] = logitsS[tid] - lse;
  }
}

extern "C" void kernel_launch(void* const* d_in, const int* in_sizes, int n_in,
                              void* d_out, int out_size, void* d_ws, size_t ws_size,
                              hipStream_t stream) {
  const float* x = (const float*)d_in[0];
  const int* ei = (const int*)d_in[1];
  const int E = in_sizes[1] / 2;
  const int* esrc = ei;
  const int* edst = ei + E;
  const int* et = (const int*)d_in[2];

  char* ws = (char*)d_ws;
  float* cs = (float*)ws;
  size_t off = (size_t)NGRAPH * NPER * DD * sizeof(float);
  ushortT* gBin = (ushortT*)(ws + off); off += (size_t)NGRAPH * EPER * sizeof(ushortT);
  ushortT* gOut = (ushortT*)(ws + off); off += (size_t)NGRAPH * EPER * sizeof(ushortT);
  int* pIn = (int*)(ws + off); off += (size_t)NGRAPH * NPER * sizeof(int);
  int* pOut = (int*)(ws + off); off += (size_t)NGRAPH * NPER * sizeof(int);
  int* gSE = (int*)(ws + off); off += (size_t)NGRAPH * 2 * sizeof(int);

  build_csr2<<<dim3(2 * NGRAPH), dim3(NTA), 0, stream>>>(esrc, edst, et, x, gBin,
                                                         gOut, pIn, pOut, gSE);
  rgcn_layer5<NFEAT><<<dim3(2 * NGRAPH), dim3(512), 0, stream>>>(
      x, cs, gBin, pIn, (const float*)d_in[4], (const float*)d_in[5],
      (const float*)d_in[6], (const float*)d_in[7], 0);
  rgcn_layer5<32><<<dim3(2 * NGRAPH), dim3(512), 0, stream>>>(
      x, cs, gBin, pIn, (const float*)d_in[8], (const float*)d_in[9],
      (const float*)d_in[10], (const float*)d_in[11], 1);
  rgcn_layer5<32><<<dim3(2 * NGRAPH), dim3(512), 0, stream>>>(
      x, cs, gBin, pIn, (const float*)d_in[12], (const float*)d_in[13],
      (const float*)d_in[14], (const float*)d_in[15], 2);
  rgcn_layer5<32><<<dim3(2 * NGRAPH), dim3(512), 0, stream>>>(
      x, cs, gBin, pIn, (const float*)d_in[16], (const float*)d_in[17],
      (const float*)d_in[18], (const float*)d_in[19], 3);
  walk_head2<<<dim3(NGRAPH), dim3(256), 0, stream>>>(
      cs, gOut, pOut, gSE, (const float*)d_in[20], (const float*)d_in[21],
      (const float*)d_in[22], (const float*)d_in[23], (const float*)d_in[24],
      (const float*)d_in[25], (float*)d_out);
}

// Round 7
// 178.246 us; speedup vs baseline: 5.5475x; 4.2122x over previous
//
#include <hip/hip_runtime.h>
#include <math.h>

#define NGRAPH 128
#define NPER   512
#define EPER   8192
#define NFEAT  4
#define NREL   5
#define DD     128
#define MAXNB  50
#define MAXW   21
#define NCLS   5

typedef unsigned short ushortT;
typedef unsigned char ucharT;

// ===================== Kernel A: build sorted in/out CSRs (proven r3-r6) =====================
#define NTA 1024

__device__ __forceinline__ void scanExcl(const int* cnt, int* offs, int* tA,
                                         int* tB, int tid) {
  if (tid < NPER) tA[tid] = cnt[tid];
  __syncthreads();
  int* a = tA; int* b = tB;
  for (int d = 1; d < NPER; d <<= 1) {
    if (tid < NPER) {
      int v = a[tid];
      if (tid >= d) v += a[tid - d];
      b[tid] = v;
    }
    __syncthreads();
    int* t = a; a = b; b = t;
  }
  if (tid < NPER) offs[tid] = a[tid] - cnt[tid];
  __syncthreads();
}

__global__ __launch_bounds__(NTA, 1)
void build_csr2(const int* __restrict__ esrc, const int* __restrict__ edst,
                const int* __restrict__ etype, const float* __restrict__ x,
                ushortT* __restrict__ gBin, ushortT* __restrict__ gOut,
                int* __restrict__ pIn, int* __restrict__ pOut,
                int* __restrict__ gSE) {
  __shared__ int keyS[EPER];
  __shared__ int auxS[EPER];
  __shared__ ushortT nodS[EPER];
  __shared__ ucharT etyS[EPER];
  __shared__ int cnt[NPER], offs[NPER], fill[NPER];
  __shared__ int se[2];
  const int bid = blockIdx.x, tid = threadIdx.x;
  const int half = bid >> 7;             // 0: in-CSR, 1: out-CSR
  const int g = bid & 127;
  const int nbase = g * NPER, ebase = g * EPER;

  if (tid < NPER) { cnt[tid] = 0; fill[tid] = 0; }
  if (tid < 2) se[tid] = NPER;
  __syncthreads();

  if (half == 0) {
    for (int e = tid; e < EPER; e += NTA) {
      auxS[e] = esrc[ebase + e] - nbase;
      etyS[e] = (ucharT)etype[ebase + e];
      int d = edst[ebase + e] - nbase;
      atomicAdd(&cnt[d], 1);
    }
    __syncthreads();
    scanExcl(cnt, offs, keyS, keyS + NPER, tid);
    for (int e = tid; e < EPER; e += NTA) {
      int d = edst[ebase + e] - nbase;
      int pos = offs[d] + atomicAdd(&fill[d], 1);
      keyS[pos] = (d << 13) | e;
    }
    __syncthreads();
    for (int p = tid; p < EPER; p += NTA) {
      const int k = keyS[p];
      const int n = k >> 13;
      const int o = offs[n], c = cnt[n];
      int r = 0;
      for (int i = 0; i < c; ++i) r += (keyS[o + i] < k);
      const int e = k & (EPER - 1);
      gBin[(size_t)g * EPER + o + r] = (ushortT)((auxS[e] << 3) | (int)etyS[e]);
    }
    if (tid < NPER) pIn[nbase + tid] = (offs[tid] << 14) | cnt[tid];
  } else {
    for (int e = tid; e < EPER; e += NTA) {
      int s = esrc[ebase + e] - nbase;
      auxS[e] = s;
      atomicAdd(&cnt[s], 1);
    }
    if (tid < NPER) {
      if (x[(size_t)(nbase + tid) * NFEAT + 0] > 0.5f) atomicMin(&se[0], tid);
      if (x[(size_t)(nbase + tid) * NFEAT + 1] > 0.5f) atomicMin(&se[1], tid);
    }
    __syncthreads();
    scanExcl(cnt, offs, keyS, keyS + NPER, tid);
    for (int e = tid; e < EPER; e += NTA) {
      int s = auxS[e];
      int d = edst[ebase + e] - nbase;
      int pos = offs[s] + atomicAdd(&fill[s], 1);
      keyS[pos] = (d << 13) | e;
      nodS[pos] = (ushortT)s;
    }
    __syncthreads();
    for (int p = tid; p < EPER; p += NTA) {
      const int k = keyS[p];
      const int n = (int)nodS[p];
      const int o = offs[n], c = cnt[n];
      int r = 0;
      for (int i = 0; i < c; ++i) r += (keyS[o + i] < k);
      gOut[(size_t)g * EPER + o + r] = (ushortT)(k >> 13);
    }
    if (tid < NPER) pOut[nbase + tid] = (offs[tid] << 14) | cnt[tid];
    if (tid < 2) gSE[g * 2 + tid] = (se[tid] >= NPER) ? 0 : se[tid];
  }
}

// ===================== Kernel B: RGCN layer as LDS GEMM (verbatim round 3, fastest) =====================
template <int FIN>
__global__ __launch_bounds__(512, 1)
void rgcn_layer2(const float* __restrict__ x, float* __restrict__ cs,
                 const ushortT* __restrict__ gBin, const int* __restrict__ pIn,
                 const float* __restrict__ bas, const float* __restrict__ cmp,
                 const float* __restrict__ rt, const float* __restrict__ bi,
                 int l) {
  constexpr int NK4 = (3 * FIN) / 4;     // k4 planes: u0, u1, h
  constexpr int LPN = FIN / 4;           // gather lanes per node
  __shared__ float A_s[NK4 * 256 * 4];
  __shared__ float Bt_s[NK4 * 32 * 4];
  __shared__ float compS[NREL * 2];
  const int bid = blockIdx.x, tid = threadIdx.x;
  const int g = bid >> 1, half = bid & 1;
  const int nbase = g * NPER;
  const int nb2 = nbase + half * 256;    // this block's first graph-node

  // ---- stage B = [bas0; bas1; rt] as Bt[k4][o][c] ----
  for (int idx = tid; idx < NK4 * 128; idx += 512) {
    const int k4 = idx >> 7, rem = idx & 127;
    const int o = rem >> 2, c = rem & 3;
    const int k = k4 * 4 + c;
    float v;
    if (k < FIN) v = bas[k * 32 + o];
    else if (k < 2 * FIN) v = bas[(FIN + (k - FIN)) * 32 + o];
    else v = rt[(k - 2 * FIN) * 32 + o];
    Bt_s[(k4 * 32 + o) * 4 + c] = v;
  }
  if (tid < NREL * 2) compS[tid] = cmp[tid];
  // ---- stage h-part of A (planes 2*LPN .. 3*LPN-1) ----
  for (int idx = tid; idx < 256 * LPN; idx += 512) {
    const int n = idx / LPN, kq = idx % LPN;
    float4 hv;
    if constexpr (FIN == 4)
      hv = *(const float4*)(x + (size_t)(nb2 + n) * NFEAT);
    else
      hv = *(const float4*)(cs + (size_t)(nb2 + n) * DD + (l - 1) * 32 + kq * 4);
    *(float4*)&A_s[((2 * LPN + kq) * 256 + n) * 4] = hv;
  }
  __syncthreads();

  // ---- gather: u_b[n][k-quad q] over sorted in-edges, scaled by 1/deg ----
  for (int t = tid; t < 256 * LPN; t += 512) {
    const int n = t / LPN, q = t % LPN;
    const int pk = pIn[nb2 + n];
    const int off = pk >> 14, c = pk & 16383;
    const float inv = 1.0f / (float)(c > 1 ? c : 1);
    float4 s0 = make_float4(0.f, 0.f, 0.f, 0.f);
    float4 s1 = make_float4(0.f, 0.f, 0.f, 0.f);
    const ushortT* el = gBin + (size_t)g * EPER + off;
    for (int i = 0; i < c; ++i) {
      const int pe = (int)el[i];
      const int s = pe >> 3, r = pe & 7;
      float4 hv;
      if constexpr (FIN == 4)
        hv = *(const float4*)(x + (size_t)(nbase + s) * NFEAT);
      else
        hv = *(const float4*)(cs + (size_t)(nbase + s) * DD + (l - 1) * 32 + q * 4);
      const float c0 = compS[r * 2 + 0], c1 = compS[r * 2 + 1];
      s0.x = fmaf(c0, hv.x, s0.x); s0.y = fmaf(c0, hv.y, s0.y);
      s0.z = fmaf(c0, hv.z, s0.z); s0.w = fmaf(c0, hv.w, s0.w);
      s1.x = fmaf(c1, hv.x, s1.x); s1.y = fmaf(c1, hv.y, s1.y);
      s1.z = fmaf(c1, hv.z, s1.z); s1.w = fmaf(c1, hv.w, s1.w);
    }
    s0.x *= inv; s0.y *= inv; s0.z *= inv; s0.w *= inv;
    s1.x *= inv; s1.y *= inv; s1.z *= inv; s1.w *= inv;
    *(float4*)&A_s[(q * 256 + n) * 4] = s0;
    *(float4*)&A_s[((LPN + q) * 256 + n) * 4] = s1;
  }
  __syncthreads();

  // ---- GEMM: thread tile 2 nodes x 8 outs ----
  const int ot = (tid >> 4) & 3;
  const int nt = (tid & 15) | ((tid >> 6) << 4);
  const int n0 = 2 * nt, o0 = 8 * ot;
  float acc[2][8];
#pragma unroll
  for (int i = 0; i < 2; ++i)
#pragma unroll
    for (int j = 0; j < 8; ++j) acc[i][j] = 0.f;
  for (int k4 = 0; k4 < NK4; ++k4) {
    const float4 a0 = *(const float4*)&A_s[(k4 * 256 + n0) * 4];
    const float4 a1 = *(const float4*)&A_s[(k4 * 256 + n0 + 1) * 4];
#pragma unroll
    for (int j = 0; j < 8; ++j) {
      const float4 b = *(const float4*)&Bt_s[(k4 * 32 + o0 + j) * 4];
      acc[0][j] = fmaf(a0.x, b.x, acc[0][j]);
      acc[0][j] = fmaf(a0.y, b.y, acc[0][j]);
      acc[0][j] = fmaf(a0.z, b.z, acc[0][j]);
      acc[0][j] = fmaf(a0.w, b.w, acc[0][j]);
      acc[1][j] = fmaf(a1.x, b.x, acc[1][j]);
      acc[1][j] = fmaf(a1.y, b.y, acc[1][j]);
      acc[1][j] = fmaf(a1.z, b.z, acc[1][j]);
      acc[1][j] = fmaf(a1.w, b.w, acc[1][j]);
    }
  }
#pragma unroll
  for (int i = 0; i < 2; ++i) {
    float4 w0, w1;
    w0.x = tanhf(acc[i][0] + bi[o0 + 0]); w0.y = tanhf(acc[i][1] + bi[o0 + 1]);
    w0.z = tanhf(acc[i][2] + bi[o0 + 2]); w0.w = tanhf(acc[i][3] + bi[o0 + 3]);
    w1.x = tanhf(acc[i][4] + bi[o0 + 4]); w1.y = tanhf(acc[i][5] + bi[o0 + 5]);
    w1.z = tanhf(acc[i][6] + bi[o0 + 6]); w1.w = tanhf(acc[i][7] + bi[o0 + 7]);
    float* dst = cs + (size_t)(nb2 + n0 + i) * DD + l * 32 + o0;
    *(float4*)dst = w0;
    *(float4*)(dst + 4) = w1;
  }
}

// ===================== Kernel C: walk + MLP head (verbatim round 4, proven) =====================
__global__ __launch_bounds__(256, 1)
void walk_head2(const float* __restrict__ cs, const ushortT* __restrict__ gOut,
                const int* __restrict__ pOut, const int* __restrict__ gSE,
                const float* __restrict__ walk_w, const float* __restrict__ walk_b,
                const float* __restrict__ lin1_w, const float* __restrict__ lin1_b,
                const float* __restrict__ lin2_w, const float* __restrict__ lin2_b,
                float* __restrict__ out) {
  __shared__ float wT[DD * 65];
  __shared__ float wb[64];
  __shared__ ushortT gOutS[EPER];
  __shared__ int pOutS[NPER];
  __shared__ int trav[NPER];
  __shared__ float scratch[MAXNB * DD];
  __shared__ float accS[DD];
  __shared__ float part[4 * 64];
  __shared__ float hidS[DD], pooledS[DD], logitsS[8];
  __shared__ int scal[8];
  const int g = blockIdx.x, tid = threadIdx.x;
  const int nbase = g * NPER;
  const float4* cs4 = (const float4*)cs;

  for (int i = tid; i < DD * 64; i += 256) {
    const int j = i >> 7, k = i & 127;
    wT[k * 65 + j] = walk_w[j * DD + k];
  }
  if (tid < 64) {
    wb[tid] = (tid < MAXNB) ? walk_b[tid] : 0.f;
    for (int k = 0; k < DD; ++k)
      if (tid >= MAXNB) wT[k * 65 + tid] = 0.f;
  }
  {
    const unsigned int* g32 = (const unsigned int*)(gOut + (size_t)g * EPER);
    unsigned int* s32 = (unsigned int*)gOutS;
    for (int i = tid; i < EPER / 2; i += 256) s32[i] = g32[i];
    for (int i = tid; i < NPER; i += 256) {
      pOutS[i] = pOut[nbase + i];
      trav[i] = 0;
    }
  }
  __syncthreads();
  const int startN = gSE[2 * g];
  const int endN = gSE[2 * g + 1];
  if (tid == 0) { scal[0] = startN; scal[1] = 0; scal[6] = 0; trav[startN] = 1; }
  if (tid < DD) accS[tid] = cs[(size_t)(nbase + startN) * DD + tid];
  __syncthreads();

  for (int step = 0; step < MAXW; ++step) {
    const int doneF = scal[1];
    int jmax = 0;
    if (!doneF) {
      const int node = scal[0];
      const int pk = pOutS[node];
      const int off = pk >> 14, c = pk & 16383;
      jmax = (c < MAXNB) ? c : MAXNB;
      const int nq = jmax * 32;
      float4 pf0, pf1, pf2, pf3, pf4, pf5, pf6;
      const int q0 = tid, q1 = tid + 256, q2 = tid + 512, q3 = tid + 768;
      const int q4 = tid + 1024, q5 = tid + 1280, q6 = tid + 1536;
      if (q0 < nq) pf0 = cs4[(size_t)(nbase + (int)gOutS[off + (q0 >> 5)]) * 32 + (q0 & 31)];
      if (q1 < nq) pf1 = cs4[(size_t)(nbase + (int)gOutS[off + (q1 >> 5)]) * 32 + (q1 & 31)];
      if (q2 < nq) pf2 = cs4[(size_t)(nbase + (int)gOutS[off + (q2 >> 5)]) * 32 + (q2 & 31)];
      if (q3 < nq) pf3 = cs4[(size_t)(nbase + (int)gOutS[off + (q3 >> 5)]) * 32 + (q3 & 31)];
      if (q4 < nq) pf4 = cs4[(size_t)(nbase + (int)gOutS[off + (q4 >> 5)]) * 32 + (q4 & 31)];
      if (q5 < nq) pf5 = cs4[(size_t)(nbase + (int)gOutS[off + (q5 >> 5)]) * 32 + (q5 & 31)];
      if (q6 < nq) pf6 = cs4[(size_t)(nbase + (int)gOutS[off + (q6 >> 5)]) * 32 + (q6 & 31)];
      {
        const int w = tid >> 6, j = tid & 63, k0 = w * 32;
        float s = 0.f;
#pragma unroll
        for (int k = 0; k < 32; ++k) s += wT[(k0 + k) * 65 + j] * accS[k0 + k];
        part[w * 64 + j] = s;
      }
      float4* scr4 = (float4*)scratch;
      if (q0 < nq) scr4[q0] = pf0;
      if (q1 < nq) scr4[q1] = pf1;
      if (q2 < nq) scr4[q2] = pf2;
      if (q3 < nq) scr4[q3] = pf3;
      if (q4 < nq) scr4[q4] = pf4;
      if (q5 < nq) scr4[q5] = pf5;
      if (q6 < nq) scr4[q6] = pf6;
    }
    __syncthreads();
    if (doneF) {
      if (tid == 0) scal[2] = 0;
    } else if (tid < 64) {
      const int j = tid;
      float lg = part[j] + part[64 + j] + part[128 + j] + part[192 + j];
      lg += wb[j];
      const int node = scal[0];
      const int pk = pOutS[node];
      const int off = pk >> 14, c = pk & 16383;
      const int jm = (c < MAXNB) ? c : MAXNB;
      float myval = -INFINITY;
      if (j < jm) {
        const int nb = (int)gOutS[off + j];
        if (!trav[nb]) myval = lg;
      }
      int myidx = j;
#pragma unroll
      for (int o = 1; o < 64; o <<= 1) {
        const float ov = __shfl_xor(myval, o, 64);
        const int oi = __shfl_xor(myidx, o, 64);
        if (ov > myval || (ov == myval && oi < myidx)) { myval = ov; myidx = oi; }
      }
      if (j == 0) {
        const int no_nbr = (c == 0);
        const int sel = no_nbr ? (NPER - 1) : (int)gOutS[off + myidx];
        scal[2] = 1;
        scal[3] = no_nbr ? endN : sel;
        scal[4] = no_nbr ? -1 : myidx;
        if (!no_nbr) { trav[sel] = 1; scal[0] = sel; }
        if (no_nbr || sel == endN) scal[1] = 1;
      }
    }
    __syncthreads();
    if (scal[2] && tid < DD) {
      const int si = scal[4];
      if (si >= 0) accS[tid] += scratch[si * DD + tid];
      else accS[tid] += cs[(size_t)(nbase + scal[3]) * DD + tid];
    }
    __syncthreads();
  }

  for (int i = tid; i < NPER; i += 256)
    if (trav[i]) atomicAdd(&scal[6], 1);
  __syncthreads();
  {
    const float tc = (float)scal[6];
    if (tid < DD) pooledS[tid] = accS[tid] / tc;
  }
  __syncthreads();
  if (tid < DD) {
    const float4* w4 = (const float4*)(lin1_w + (size_t)tid * DD);
    float s = lin1_b[tid];
#pragma unroll 8
    for (int k4 = 0; k4 < DD / 4; ++k4) {
      const float4 wv = w4[k4];
      s += wv.x * pooledS[k4 * 4 + 0] + wv.y * pooledS[k4 * 4 + 1]
         + wv.z * pooledS[k4 * 4 + 2] + wv.w * pooledS[k4 * 4 + 3];
    }
    hidS[tid] = fmaxf(s, 0.f);
  }
  __syncthreads();
  if (tid < NCLS) {
    const float4* w4 = (const float4*)(lin2_w + (size_t)tid * DD);
    float s = lin2_b[tid];
#pragma unroll 8
    for (int k4 = 0; k4 < DD / 4; ++k4) {
      const float4 wv = w4[k4];
      s += wv.x * hidS[k4 * 4 + 0] + wv.y * hidS[k4 * 4 + 1]
         + wv.z * hidS[k4 * 4 + 2] + wv.w * hidS[k4 * 4 + 3];
    }
    logitsS[tid] = s;
  }
  __syncthreads();
  if (tid < NCLS) {
    float m = logitsS[0];
    for (int c = 1; c < NCLS; ++c) m = fmaxf(m, logitsS[c]);
    float sum = 0.f;
    for (int c = 0; c < NCLS; ++c) sum += expf(logitsS[c] - m);
    const float lse = m + logf(sum);
    out[g * NCLS + tid] = logitsS[tid] - lse;
  }
}

extern "C" void kernel_launch(void* const* d_in, const int* in_sizes, int n_in,
                              void* d_out, int out_size, void* d_ws, size_t ws_size,
                              hipStream_t stream) {
  const float* x = (const float*)d_in[0];
  const int* ei = (const int*)d_in[1];
  const int E = in_sizes[1] / 2;
  const int* esrc = ei;
  const int* edst = ei + E;
  const int* et = (const int*)d_in[2];

  char* ws = (char*)d_ws;
  float* cs = (float*)ws;
  size_t off = (size_t)NGRAPH * NPER * DD * sizeof(float);
  ushortT* gBin = (ushortT*)(ws + off); off += (size_t)NGRAPH * EPER * sizeof(ushortT);
  ushortT* gOut = (ushortT*)(ws + off); off += (size_t)NGRAPH * EPER * sizeof(ushortT);
  int* pIn = (int*)(ws + off); off += (size_t)NGRAPH * NPER * sizeof(int);
  int* pOut = (int*)(ws + off); off += (size_t)NGRAPH * NPER * sizeof(int);
  int* gSE = (int*)(ws + off); off += (size_t)NGRAPH * 2 * sizeof(int);

  build_csr2<<<dim3(2 * NGRAPH), dim3(NTA), 0, stream>>>(esrc, edst, et, x, gBin,
                                                         gOut, pIn, pOut, gSE);
  rgcn_layer2<NFEAT><<<dim3(2 * NGRAPH), dim3(512), 0, stream>>>(
      x, cs, gBin, pIn, (const float*)d_in[4], (const float*)d_in[5],
      (const float*)d_in[6], (const float*)d_in[7], 0);
  rgcn_layer2<32><<<dim3(2 * NGRAPH), dim3(512), 0, stream>>>(
      x, cs, gBin, pIn, (const float*)d_in[8], (const float*)d_in[9],
      (const float*)d_in[10], (const float*)d_in[11], 1);
  rgcn_layer2<32><<<dim3(2 * NGRAPH), dim3(512), 0, stream>>>(
      x, cs, gBin, pIn, (const float*)d_in[12], (const float*)d_in[13],
      (const float*)d_in[14], (const float*)d_in[15], 2);
  rgcn_layer2<32><<<dim3(2 * NGRAPH), dim3(512), 0, stream>>>(
      x, cs, gBin, pIn, (const float*)d_in[16], (const float*)d_in[17],
      (const float*)d_in[18], (const float*)d_in[19], 3);
  walk_head2<<<dim3(NGRAPH), dim3(256), 0, stream>>>(
      cs, gOut, pOut, gSE, (const float*)d_in[20], (const float*)d_in[21],
      (const float*)d_in[22], (const float*)d_in[23], (const float*)d_in[24],
      (const float*)d_in[25], (float*)d_out);
}